// Round 2
// baseline (1078.031 us; speedup 1.0000x reference)
//
#include <hip/hip_runtime.h>
#include <hip/hip_bf16.h>

// (B,S,H,A,D) = (16, 4096, 1024, 1024, 6), all f32.
#define Bn 16
#define Sn 4096
#define Hn 1024
#define An 1024
#define Dn 6
#define TOK_PER_BLK 32
#define NBLOCKS (Bn * Sn / TOK_PER_BLK)   // 2048

constexpr float LN_EPS_F = 1e-5f;

__device__ __forceinline__ float rcp_fast(float x) { return __builtin_amdgcn_rcpf(x); }
__device__ __forceinline__ float fast_sigmoid(float x) { return rcp_fast(1.f + __expf(-x)); }
__device__ __forceinline__ float fast_tanh(float x) {
    float ax = fabsf(x);
    float z  = __expf(-2.f * ax);
    float t  = (1.f - z) * rcp_fast(1.f + z);
    return copysignf(t, x);
}
__device__ __forceinline__ float gelu_exact(float x) {
    return 0.5f * x * (1.f + erff(x * 0.7071067811865476f));
}
__device__ __forceinline__ float wred(float v) {
    #pragma unroll
    for (int m = 1; m < 64; m <<= 1) v += __shfl_xor(v, m, 64);
    return v;
}
// f32 -> bf16 (round-nearest-even); inputs here are finite
__device__ __forceinline__ unsigned short f2bf(float f) {
    unsigned u = __float_as_uint(f);
    u = (u + 0x7fffu + ((u >> 16) & 1u)) >> 16;
    return (unsigned short)u;
}
// unpack two bf16 packed in a u32 (lo = elem0, hi = elem1)
__device__ __forceinline__ void bf2x(unsigned u, float& f0, float& f1) {
    f0 = __uint_as_float(u << 16);
    f1 = __uint_as_float(u & 0xffff0000u);
}

// ---------------- pre-kernel: per-batch CLS context + scalar gate, and CB[d]=sum beta*W[d] ----------------
// grid = 17 blocks x 64 threads. ws layout (floats):
//   ws[b*8 + d] = sctx[b][d] (d<6), ws[b*8+6] = gate[b]   for b<16
//   ws[128 + d] = CB[d], d=0..6  (rows 0..5 = Wr, row 6 = Wtg)
__global__ __launch_bounds__(64) void pre_kernel(
    const float* __restrict__ attn, const float* __restrict__ gamma,
    const float* __restrict__ beta, const float* __restrict__ Wr,
    const float* __restrict__ Wc,   const float* __restrict__ Wtg,
    const float* __restrict__ Wsg,  const float* __restrict__ bsg,
    float* __restrict__ ws)
{
    const int blk = blockIdx.x;
    const int l   = threadIdx.x;
    if (blk < Bn) {
        const float4* ar = reinterpret_cast<const float4*>(attn + (size_t)blk * Sn * An);
        float4 x[4], g4[4], be4[4];
        #pragma unroll
        for (int e = 0; e < 4; e++) {
            x[e]  = ar[l + 64 * e];
            g4[e] = reinterpret_cast<const float4*>(gamma)[l + 64 * e];
            be4[e]= reinterpret_cast<const float4*>(beta)[l + 64 * e];
        }
        float s = 0.f, ss = 0.f;
        #pragma unroll
        for (int e = 0; e < 4; e++) {
            s  += x[e].x + x[e].y + x[e].z + x[e].w;
            ss += x[e].x*x[e].x + x[e].y*x[e].y + x[e].z*x[e].z + x[e].w*x[e].w;
        }
        #pragma unroll
        for (int m = 1; m < 64; m <<= 1) { s += __shfl_xor(s, m, 64); ss += __shfl_xor(ss, m, 64); }
        float mu   = s * (1.f / An);
        float var  = ss * (1.f / An) - mu * mu;
        float rstd = rsqrtf(var + LN_EPS_F);
        #pragma unroll
        for (int e = 0; e < 4; e++) {
            x[e].x = (x[e].x - mu) * rstd * g4[e].x + be4[e].x;
            x[e].y = (x[e].y - mu) * rstd * g4[e].y + be4[e].y;
            x[e].z = (x[e].z - mu) * rstd * g4[e].z + be4[e].z;
            x[e].w = (x[e].w - mu) * rstd * g4[e].w + be4[e].w;
        }
        float accr[6] = {}, accc[6] = {};
        #pragma unroll
        for (int e = 0; e < 4; e++) {
            #pragma unroll
            for (int d = 0; d < 6; d++) {
                float4 wr = reinterpret_cast<const float4*>(Wr)[d * 256 + l + 64 * e];
                float4 wc = reinterpret_cast<const float4*>(Wc)[d * 256 + l + 64 * e];
                accr[d] += x[e].x*wr.x + x[e].y*wr.y + x[e].z*wr.z + x[e].w*wr.w;
                accc[d] += x[e].x*wc.x + x[e].y*wc.y + x[e].z*wc.z + x[e].w*wc.w;
            }
        }
        float gsum = 0.f, sctx[6];
        #pragma unroll
        for (int d = 0; d < 6; d++) {
            float r = wred(accr[d]);
            float c = wred(accc[d]);
            sctx[d] = c;                       // CLS_CONTEXT_SCALE = 1.0
            gsum += gelu_exact(r + c) * Wsg[d];
        }
        float gate = fast_sigmoid(gsum + bsg[0]);
        if (l < 6)  ws[blk * 8 + l] = sctx[l];
        if (l == 6) ws[blk * 8 + 6] = gate;
    } else {
        // CB[d] = sum_a beta[a] * Wraw[d][a]
        float cb[7] = {};
        #pragma unroll
        for (int e = 0; e < 4; e++) {
            float4 be = reinterpret_cast<const float4*>(beta)[l + 64 * e];
            #pragma unroll
            for (int d = 0; d < 7; d++) {
                float4 wv = (d < 6) ? reinterpret_cast<const float4*>(Wr)[d * 256 + l + 64 * e]
                                    : reinterpret_cast<const float4*>(Wtg)[l + 64 * e];
                cb[d] += be.x*wv.x + be.y*wv.y + be.z*wv.z + be.w*wv.w;
            }
        }
        #pragma unroll
        for (int d = 0; d < 7; d++) {
            float c = wred(cb[d]);
            if (l == 0) ws[128 + d] = c;
        }
    }
}

// ---------------- main kernel ----------------
// One wave per token. Weights staged once per block as gamma-folded bf16.
// LDS = 14336 (WT) + 12288 (WeT) + 4096 (Ls) = 30720 B -> 5 blocks/CU by LDS.
__global__ __launch_bounds__(256, 5) void fused_main_kernel(
    const float* __restrict__ hidden,
    const float* __restrict__ attn,
    const float* __restrict__ gamma,
    const float* __restrict__ Wr,     // [6][1024]
    const float* __restrict__ We,     // [1024][6]
    const float* __restrict__ Wtg,    // [1][1024]
    const float* __restrict__ btg,    // [1]
    const float* __restrict__ lsc,    // [1][1][1024]
    const float* __restrict__ ws,     // pre-kernel results
    float* __restrict__ out)
{
    __shared__ __align__(16) unsigned short WT[7 * An];   // gamma-folded Wr rows 0..5 + Wtg, bf16
    __shared__ __align__(16) unsigned short WeT[Dn * Hn]; // We transposed [d][h], bf16
    __shared__ __align__(16) float Ls[Hn];                // layer_scale, f32

    const int tid = threadIdx.x;
    const int l   = tid & 63;
    const int w   = tid >> 6;

    for (int i = tid; i < 7 * An; i += 256) {
        int a = i & 1023;
        float wv = (i < 6 * An) ? Wr[i] : Wtg[a];
        WT[i] = f2bf(wv * gamma[a]);
    }
    for (int i = tid; i < Dn * Hn; i += 256) {
        unsigned h = (unsigned)i / 6u;
        int d = i - (int)h * 6;
        WeT[d * Hn + h] = f2bf(We[i]);
    }
    for (int i = tid; i < Hn; i += 256) Ls[i] = lsc[i];

    const int  blk = blockIdx.x;
    const int  b   = blk >> 7;                 // 128 blocks per batch
    const long t0  = (long)blk * TOK_PER_BLK;

    // uniform scalars (s_load-able)
    float sctx0 = ws[b*8+0], sctx1 = ws[b*8+1], sctx2 = ws[b*8+2];
    float sctx3 = ws[b*8+3], sctx4 = ws[b*8+4], sctx5 = ws[b*8+5];
    const float gate = ws[b*8+6];
    float CB[7];
    #pragma unroll
    for (int d = 0; d < 7; d++) CB[d] = ws[128 + d];
    const float btg0 = btg[0];

    __syncthreads();

    // per-lane partial row-sums of the folded weights: gw[d] = sum over this lane's 16 elems of W'[d]
    float gw[7];
    #pragma unroll
    for (int d = 0; d < 7; d++) {
        float acc = 0.f;
        #pragma unroll
        for (int e = 0; e < 4; e++) {
            uint2 u = *reinterpret_cast<const uint2*>(WT + d * An + 4 * l + 256 * e);
            float w0,w1,w2,w3; bf2x(u.x, w0, w1); bf2x(u.y, w2, w3);
            acc += (w0 + w1) + (w2 + w3);
        }
        gw[d] = acc;
    }

    const float sctx[6] = {sctx0, sctx1, sctx2, sctx3, sctx4, sctx5};

    #pragma unroll 1
    for (int it = 0; it < TOK_PER_BLK / 4; ++it) {
        const long t = t0 + w + 4 * it;
        const float4* ar = reinterpret_cast<const float4*>(attn + (size_t)t * An);
        float4 x[4];
        #pragma unroll
        for (int e = 0; e < 4; e++) x[e] = ar[l + 64 * e];

        float s = 0.f, ss = 0.f;
        #pragma unroll
        for (int e = 0; e < 4; e++) {
            s  += x[e].x + x[e].y + x[e].z + x[e].w;
            ss += x[e].x*x[e].x + x[e].y*x[e].y + x[e].z*x[e].z + x[e].w*x[e].w;
        }
        #pragma unroll
        for (int m = 1; m < 64; m <<= 1) { s += __shfl_xor(s, m, 64); ss += __shfl_xor(ss, m, 64); }
        const float mu   = s * (1.f / An);
        const float var  = ss * (1.f / An) - mu * mu;
        const float rstd = rsqrtf(var + LN_EPS_F);

        // p[d] = sum over lane's elems of x * W'  (bf16 LDS, uint2 = 4 elems)
        float p[7] = {};
        #pragma unroll
        for (int e = 0; e < 4; e++) {
            #pragma unroll
            for (int d = 0; d < 7; d++) {
                uint2 u = *reinterpret_cast<const uint2*>(WT + d * An + 4 * l + 256 * e);
                float w0,w1,w2,w3; bf2x(u.x, w0, w1); bf2x(u.y, w2, w3);
                p[d] += x[e].x*w0 + x[e].y*w1 + x[e].z*w2 + x[e].w*w3;
            }
        }
        #pragma unroll
        for (int d = 0; d < 7; d++) p[d] -= mu * gw[d];

        // hidden row: issue now, consumed after the reduction chain
        const float4* hr = reinterpret_cast<const float4*>(hidden + (size_t)t * Hn);
        float4 hd[4];
        #pragma unroll
        for (int e = 0; e < 4; e++) hd[e] = hr[l + 64 * e];

        #pragma unroll
        for (int d = 0; d < 7; d++) p[d] = wred(p[d]);

        float th[6];
        #pragma unroll
        for (int d = 0; d < 6; d++) th[d] = gelu_exact(rstd * p[d] + CB[d] + sctx[d]);
        const float tg = fast_sigmoid(rstd * p[6] + CB[6] + btg0);
        const float K  = gate * tg;

        float4* orow = reinterpret_cast<float4*>(out + (size_t)t * Hn);
        #pragma unroll
        for (int e = 0; e < 4; e++) {
            float mi0 = 0.f, mi1 = 0.f, mi2 = 0.f, mi3 = 0.f;
            #pragma unroll
            for (int d = 0; d < 6; d++) {
                uint2 u = *reinterpret_cast<const uint2*>(WeT + d * Hn + 4 * l + 256 * e);
                float w0,w1,w2,w3; bf2x(u.x, w0, w1); bf2x(u.y, w2, w3);
                mi0 += th[d]*w0; mi1 += th[d]*w1; mi2 += th[d]*w2; mi3 += th[d]*w3;
            }
            float4 lsv = *reinterpret_cast<const float4*>(Ls + 4 * l + 256 * e);
            float4 hv = hd[e], o;
            o.x = hv.x * (1.f + K * lsv.x * fast_tanh(mi0));
            o.y = hv.y * (1.f + K * lsv.y * fast_tanh(mi1));
            o.z = hv.z * (1.f + K * lsv.z * fast_tanh(mi2));
            o.w = hv.w * (1.f + K * lsv.w * fast_tanh(mi3));
            orow[l + 64 * e] = o;
        }
    }
}

extern "C" void kernel_launch(void* const* d_in, const int* in_sizes, int n_in,
                              void* d_out, int out_size, void* d_ws, size_t ws_size,
                              hipStream_t stream) {
    const float* hidden = (const float*)d_in[0];
    const float* attn   = (const float*)d_in[1];
    const float* gamma  = (const float*)d_in[2];
    const float* beta   = (const float*)d_in[3];
    const float* Wr     = (const float*)d_in[4];
    const float* Wc     = (const float*)d_in[5];
    const float* We     = (const float*)d_in[6];
    const float* Wtg    = (const float*)d_in[7];
    const float* btg    = (const float*)d_in[8];
    const float* Wsg    = (const float*)d_in[9];
    const float* bsg    = (const float*)d_in[10];
    const float* lsc    = (const float*)d_in[11];
    float* out = (float*)d_out;
    float* ws  = (float*)d_ws;

    pre_kernel<<<dim3(Bn + 1), dim3(64), 0, stream>>>(attn, gamma, beta, Wr, Wc, Wtg, Wsg, bsg, ws);
    fused_main_kernel<<<dim3(NBLOCKS), dim3(256), 0, stream>>>(
        hidden, attn, gamma, Wr, We, Wtg, btg, lsc, ws, out);
}

// Round 3
// 397.355 us; speedup vs baseline: 2.7130x; 2.7130x over previous
//
#include <hip/hip_runtime.h>
#include <hip/hip_bf16.h>

// (B,S,H,A,D) = (16, 4096, 1024, 1024, 6), all f32.
#define Bn 16
#define Sn 4096
#define Hn 1024
#define An 1024
#define Dn 6
#define TOK_PER_BLK 32
#define NBLOCKS (Bn * Sn / TOK_PER_BLK)   // 2048
#define WS_TH_BASE 256                     // float offset of th-table in ws

constexpr float LN_EPS_F = 1e-5f;

__device__ __forceinline__ float rcp_fast(float x) { return __builtin_amdgcn_rcpf(x); }
__device__ __forceinline__ float fast_sigmoid(float x) { return rcp_fast(1.f + __expf(-x)); }
__device__ __forceinline__ float fast_tanh(float x) {
    float ax = fabsf(x);
    float z  = __expf(-2.f * ax);
    float t  = (1.f - z) * rcp_fast(1.f + z);
    return copysignf(t, x);
}
__device__ __forceinline__ float gelu_exact(float x) {
    return 0.5f * x * (1.f + erff(x * 0.7071067811865476f));
}
__device__ __forceinline__ float wred(float v) {
    #pragma unroll
    for (int m = 1; m < 64; m <<= 1) v += __shfl_xor(v, m, 64);
    return v;
}
__device__ __forceinline__ unsigned short f2bf(float f) {
    unsigned u = __float_as_uint(f);
    u = (u + 0x7fffu + ((u >> 16) & 1u)) >> 16;
    return (unsigned short)u;
}
__device__ __forceinline__ void bf2x(unsigned u, float& f0, float& f1) {
    f0 = __uint_as_float(u << 16);
    f1 = __uint_as_float(u & 0xffff0000u);
}

// ---------------- pre-kernel: per-batch CLS context + scalar gate; CB[d] = sum beta*W[d] ----------------
// ws[b*8+d] = sctx[b][d] (d<6); ws[b*8+6] = gate[b]; ws[128+d] = CB[d] (rows 0..5 Wr, 6 Wtg)
__global__ __launch_bounds__(64) void pre_kernel(
    const float* __restrict__ attn, const float* __restrict__ gamma,
    const float* __restrict__ beta, const float* __restrict__ Wr,
    const float* __restrict__ Wc,   const float* __restrict__ Wtg,
    const float* __restrict__ Wsg,  const float* __restrict__ bsg,
    float* __restrict__ ws)
{
    const int blk = blockIdx.x;
    const int l   = threadIdx.x;
    if (blk < Bn) {
        const float4* ar = reinterpret_cast<const float4*>(attn + (size_t)blk * Sn * An);
        float4 x[4], g4[4], be4[4];
        #pragma unroll
        for (int e = 0; e < 4; e++) {
            x[e]  = ar[l + 64 * e];
            g4[e] = reinterpret_cast<const float4*>(gamma)[l + 64 * e];
            be4[e]= reinterpret_cast<const float4*>(beta)[l + 64 * e];
        }
        float s = 0.f, ss = 0.f;
        #pragma unroll
        for (int e = 0; e < 4; e++) {
            s  += x[e].x + x[e].y + x[e].z + x[e].w;
            ss += x[e].x*x[e].x + x[e].y*x[e].y + x[e].z*x[e].z + x[e].w*x[e].w;
        }
        #pragma unroll
        for (int m = 1; m < 64; m <<= 1) { s += __shfl_xor(s, m, 64); ss += __shfl_xor(ss, m, 64); }
        float mu   = s * (1.f / An);
        float var  = ss * (1.f / An) - mu * mu;
        float rstd = rsqrtf(var + LN_EPS_F);
        #pragma unroll
        for (int e = 0; e < 4; e++) {
            x[e].x = (x[e].x - mu) * rstd * g4[e].x + be4[e].x;
            x[e].y = (x[e].y - mu) * rstd * g4[e].y + be4[e].y;
            x[e].z = (x[e].z - mu) * rstd * g4[e].z + be4[e].z;
            x[e].w = (x[e].w - mu) * rstd * g4[e].w + be4[e].w;
        }
        float accr[6] = {}, accc[6] = {};
        #pragma unroll
        for (int e = 0; e < 4; e++) {
            #pragma unroll
            for (int d = 0; d < 6; d++) {
                float4 wr = reinterpret_cast<const float4*>(Wr)[d * 256 + l + 64 * e];
                float4 wc = reinterpret_cast<const float4*>(Wc)[d * 256 + l + 64 * e];
                accr[d] += x[e].x*wr.x + x[e].y*wr.y + x[e].z*wr.z + x[e].w*wr.w;
                accc[d] += x[e].x*wc.x + x[e].y*wc.y + x[e].z*wc.z + x[e].w*wc.w;
            }
        }
        float gsum = 0.f, sctx[6];
        #pragma unroll
        for (int d = 0; d < 6; d++) {
            float r = wred(accr[d]);
            float c = wred(accc[d]);
            sctx[d] = c;                       // CLS_CONTEXT_SCALE = 1.0
            gsum += gelu_exact(r + c) * Wsg[d];
        }
        float gate = fast_sigmoid(gsum + bsg[0]);
        if (l < 6)  ws[blk * 8 + l] = sctx[l];
        if (l == 6) ws[blk * 8 + 6] = gate;
    } else {
        float cb[7] = {};
        #pragma unroll
        for (int e = 0; e < 4; e++) {
            float4 be = reinterpret_cast<const float4*>(beta)[l + 64 * e];
            #pragma unroll
            for (int d = 0; d < 7; d++) {
                float4 wv = (d < 6) ? reinterpret_cast<const float4*>(Wr)[d * 256 + l + 64 * e]
                                    : reinterpret_cast<const float4*>(Wtg)[l + 64 * e];
                cb[d] += be.x*wv.x + be.y*wv.y + be.z*wv.z + be.w*wv.w;
            }
        }
        #pragma unroll
        for (int d = 0; d < 7; d++) {
            float c = wred(cb[d]);
            if (l == 0) ws[128 + d] = c;
        }
    }
}

// ---------------- phase 1: attn -> per-token scalars {th[0..5], K} ----------------
// One wave per token; LDS = gamma-folded bf16 weights (14336 B). ~60 VGPRs, no spill.
__global__ __launch_bounds__(256, 4) void phase1_kernel(
    const float* __restrict__ attn,
    const float* __restrict__ gamma,
    const float* __restrict__ Wr,     // [6][1024]
    const float* __restrict__ Wtg,    // [1][1024]
    const float* __restrict__ btg,    // [1]
    float* __restrict__ ws)           // in: sctx/gate/CB; out: th-table at WS_TH_BASE
{
    __shared__ __align__(16) unsigned short WT[7 * An];

    const int tid = threadIdx.x;
    const int l   = tid & 63;
    const int w   = tid >> 6;

    for (int i = tid; i < 7 * An; i += 256) {
        int a = i & 1023;
        float wv = (i < 6 * An) ? Wr[i] : Wtg[a];
        WT[i] = f2bf(wv * gamma[a]);
    }

    const int  blk = blockIdx.x;
    const int  b   = blk >> 7;                 // 128 blocks per batch
    const long t0  = (long)blk * TOK_PER_BLK;

    const float sctx0 = ws[b*8+0], sctx1 = ws[b*8+1], sctx2 = ws[b*8+2];
    const float sctx3 = ws[b*8+3], sctx4 = ws[b*8+4], sctx5 = ws[b*8+5];
    const float gate  = ws[b*8+6];
    float CB[7];
    #pragma unroll
    for (int d = 0; d < 7; d++) CB[d] = ws[128 + d];
    const float btg0 = btg[0];

    __syncthreads();

    // per-lane partial row-sums of folded weights
    float gw[7];
    #pragma unroll
    for (int d = 0; d < 7; d++) {
        float acc = 0.f;
        #pragma unroll
        for (int e = 0; e < 4; e++) {
            uint2 u = *reinterpret_cast<const uint2*>(WT + d * An + 4 * l + 256 * e);
            float w0,w1,w2,w3; bf2x(u.x, w0, w1); bf2x(u.y, w2, w3);
            acc += (w0 + w1) + (w2 + w3);
        }
        gw[d] = acc;
    }
    const float sctx[6] = {sctx0, sctx1, sctx2, sctx3, sctx4, sctx5};

    #pragma unroll 1
    for (int it = 0; it < TOK_PER_BLK / 4; ++it) {
        const long t = t0 + w + 4 * it;
        const float4* ar = reinterpret_cast<const float4*>(attn + (size_t)t * An);
        float4 x[4];
        #pragma unroll
        for (int e = 0; e < 4; e++) x[e] = ar[l + 64 * e];

        float s = 0.f, ss = 0.f;
        #pragma unroll
        for (int e = 0; e < 4; e++) {
            s  += x[e].x + x[e].y + x[e].z + x[e].w;
            ss += x[e].x*x[e].x + x[e].y*x[e].y + x[e].z*x[e].z + x[e].w*x[e].w;
        }
        #pragma unroll
        for (int m = 1; m < 64; m <<= 1) { s += __shfl_xor(s, m, 64); ss += __shfl_xor(ss, m, 64); }
        const float mu   = s * (1.f / An);
        const float var  = ss * (1.f / An) - mu * mu;
        const float rstd = rsqrtf(var + LN_EPS_F);

        float p[7] = {};
        #pragma unroll
        for (int e = 0; e < 4; e++) {
            #pragma unroll
            for (int d = 0; d < 7; d++) {
                uint2 u = *reinterpret_cast<const uint2*>(WT + d * An + 4 * l + 256 * e);
                float w0,w1,w2,w3; bf2x(u.x, w0, w1); bf2x(u.y, w2, w3);
                p[d] += x[e].x*w0 + x[e].y*w1 + x[e].z*w2 + x[e].w*w3;
            }
        }
        #pragma unroll
        for (int d = 0; d < 7; d++) p[d] -= mu * gw[d];
        #pragma unroll
        for (int d = 0; d < 7; d++) p[d] = wred(p[d]);

        float th[6];
        #pragma unroll
        for (int d = 0; d < 6; d++) th[d] = gelu_exact(rstd * p[d] + CB[d] + sctx[d]);
        const float tg = fast_sigmoid(rstd * p[6] + CB[6] + btg0);
        const float K  = gate * tg;

        float4* tp = reinterpret_cast<float4*>(ws + WS_TH_BASE + (size_t)t * 8);
        if (l == 0) tp[0] = make_float4(th[0], th[1], th[2], th[3]);
        if (l == 1) tp[1] = make_float4(th[4], th[5], K, 0.f);
    }
}

// ---------------- phase 2: out = hidden * (1 + K * ls * tanh(We . th)) ----------------
// Pure streaming; ~45 VGPRs; LDS 17.4 KB -> 8 blocks/CU.
__global__ __launch_bounds__(256, 4) void phase2_kernel(
    const float* __restrict__ hidden,
    const float* __restrict__ We,     // [1024][6]
    const float* __restrict__ lsc,    // [1024]
    const float* __restrict__ ws,     // th-table at WS_TH_BASE
    float* __restrict__ out)
{
    __shared__ __align__(16) unsigned short WeT[Dn * Hn]; // [d][h] bf16
    __shared__ __align__(16) float Ls[Hn];
    __shared__ __align__(16) float T[TOK_PER_BLK * 8];

    const int tid = threadIdx.x;
    const int l   = tid & 63;
    const int w   = tid >> 6;
    const long t0 = (long)blockIdx.x * TOK_PER_BLK;

    // stage We transposed: thread handles h-rows (2-way-conflict writes at worst)
    for (int h = tid; h < Hn; h += 256) {
        #pragma unroll
        for (int d = 0; d < Dn; d++) WeT[d * Hn + h] = f2bf(We[h * Dn + d]);
        Ls[h] = lsc[h];
    }
    T[tid] = ws[WS_TH_BASE + t0 * 8 + tid];   // 256 floats = 32 tokens x 8
    __syncthreads();

    #pragma unroll 1
    for (int it = 0; it < TOK_PER_BLK / 4; ++it) {
        const int  tl = w + 4 * it;
        const long t  = t0 + tl;
        const float4 Ta = *reinterpret_cast<const float4*>(&T[tl * 8]);
        const float4 Tb = *reinterpret_cast<const float4*>(&T[tl * 8 + 4]);
        const float th0 = Ta.x, th1 = Ta.y, th2 = Ta.z, th3 = Ta.w;
        const float th4 = Tb.x, th5 = Tb.y, K = Tb.z;

        const float4* hr  = reinterpret_cast<const float4*>(hidden + (size_t)t * Hn);
        float4*       orw = reinterpret_cast<float4*>(out + (size_t)t * Hn);
        #pragma unroll
        for (int e = 0; e < 4; e++) {
            const int idx = l + 64 * e;
            float4 hv = hr[idx];
            float mi0 = 0.f, mi1 = 0.f, mi2 = 0.f, mi3 = 0.f;
            #pragma unroll
            for (int d = 0; d < 6; d++) {
                const float thd = (d==0)?th0:(d==1)?th1:(d==2)?th2:(d==3)?th3:(d==4)?th4:th5;
                uint2 u = *reinterpret_cast<const uint2*>(WeT + d * Hn + 4 * l + 256 * e);
                float w0,w1,w2,w3; bf2x(u.x, w0, w1); bf2x(u.y, w2, w3);
                mi0 += thd*w0; mi1 += thd*w1; mi2 += thd*w2; mi3 += thd*w3;
            }
            float4 lsv = *reinterpret_cast<const float4*>(Ls + 4 * l + 256 * e);
            float4 o;
            o.x = hv.x * (1.f + K * lsv.x * fast_tanh(mi0));
            o.y = hv.y * (1.f + K * lsv.y * fast_tanh(mi1));
            o.z = hv.z * (1.f + K * lsv.z * fast_tanh(mi2));
            o.w = hv.w * (1.f + K * lsv.w * fast_tanh(mi3));
            orw[idx] = o;
        }
    }
}

extern "C" void kernel_launch(void* const* d_in, const int* in_sizes, int n_in,
                              void* d_out, int out_size, void* d_ws, size_t ws_size,
                              hipStream_t stream) {
    const float* hidden = (const float*)d_in[0];
    const float* attn   = (const float*)d_in[1];
    const float* gamma  = (const float*)d_in[2];
    const float* beta   = (const float*)d_in[3];
    const float* Wr     = (const float*)d_in[4];
    const float* Wc     = (const float*)d_in[5];
    const float* We     = (const float*)d_in[6];
    const float* Wtg    = (const float*)d_in[7];
    const float* btg    = (const float*)d_in[8];
    const float* Wsg    = (const float*)d_in[9];
    const float* bsg    = (const float*)d_in[10];
    const float* lsc    = (const float*)d_in[11];
    float* out = (float*)d_out;
    float* ws  = (float*)d_ws;

    pre_kernel<<<dim3(Bn + 1), dim3(64), 0, stream>>>(attn, gamma, beta, Wr, Wc, Wtg, Wsg, bsg, ws);
    phase1_kernel<<<dim3(NBLOCKS), dim3(256), 0, stream>>>(attn, gamma, Wr, Wtg, btg, ws);
    phase2_kernel<<<dim3(NBLOCKS), dim3(256), 0, stream>>>(hidden, We, lsc, ws, out);
}

// Round 4
// 209.877 us; speedup vs baseline: 5.1365x; 1.8933x over previous
//
#include <hip/hip_runtime.h>
#include <hip/hip_bf16.h>

// (B,S,H,A,D) = (16, 4096, 1024, 1024, 6), all f32.
#define Bn 16
#define Sn 4096
#define Hn 1024
#define An 1024
#define Dn 6
#define TOK_PER_BLK 32
#define NBLOCKS (Bn * Sn / TOK_PER_BLK)   // 2048
#define WS_TH_BASE 256                     // float offset of th-table in ws

constexpr float LN_EPS_F = 1e-5f;

__device__ __forceinline__ float rcp_fast(float x) { return __builtin_amdgcn_rcpf(x); }
__device__ __forceinline__ float fast_sigmoid(float x) { return rcp_fast(1.f + __expf(-x)); }
__device__ __forceinline__ float fast_tanh(float x) {
    float ax = fabsf(x);
    float z  = __expf(-2.f * ax);
    float t  = (1.f - z) * rcp_fast(1.f + z);
    return copysignf(t, x);
}
__device__ __forceinline__ float gelu_exact(float x) {
    return 0.5f * x * (1.f + erff(x * 0.7071067811865476f));
}
__device__ __forceinline__ float wred(float v) {
    #pragma unroll
    for (int m = 1; m < 64; m <<= 1) v += __shfl_xor(v, m, 64);
    return v;
}
__device__ __forceinline__ unsigned short f2bf(float f) {
    unsigned u = __float_as_uint(f);
    u = (u + 0x7fffu + ((u >> 16) & 1u)) >> 16;
    return (unsigned short)u;
}
__device__ __forceinline__ void bf2x(unsigned u, float& f0, float& f1) {
    f0 = __uint_as_float(u << 16);
    f1 = __uint_as_float(u & 0xffff0000u);
}

// ---------------- pre-kernel: per-batch CLS context + scalar gate; CB[d] = sum beta*W[d] ----------------
// ws[b*8+d] = sctx[b][d] (d<6); ws[b*8+6] = gate[b]; ws[128+d] = CB[d] (rows 0..5 Wr, 6 Wtg)
__global__ __launch_bounds__(64) void pre_kernel(
    const float* __restrict__ attn, const float* __restrict__ gamma,
    const float* __restrict__ beta, const float* __restrict__ Wr,
    const float* __restrict__ Wc,   const float* __restrict__ Wtg,
    const float* __restrict__ Wsg,  const float* __restrict__ bsg,
    float* __restrict__ ws)
{
    const int blk = blockIdx.x;
    const int l   = threadIdx.x;
    if (blk < Bn) {
        const float4* ar = reinterpret_cast<const float4*>(attn + (size_t)blk * Sn * An);
        float4 x[4], g4[4], be4[4];
        #pragma unroll
        for (int e = 0; e < 4; e++) {
            x[e]  = ar[l + 64 * e];
            g4[e] = reinterpret_cast<const float4*>(gamma)[l + 64 * e];
            be4[e]= reinterpret_cast<const float4*>(beta)[l + 64 * e];
        }
        float s = 0.f, ss = 0.f;
        #pragma unroll
        for (int e = 0; e < 4; e++) {
            s  += x[e].x + x[e].y + x[e].z + x[e].w;
            ss += x[e].x*x[e].x + x[e].y*x[e].y + x[e].z*x[e].z + x[e].w*x[e].w;
        }
        #pragma unroll
        for (int m = 1; m < 64; m <<= 1) { s += __shfl_xor(s, m, 64); ss += __shfl_xor(ss, m, 64); }
        float mu   = s * (1.f / An);
        float var  = ss * (1.f / An) - mu * mu;
        float rstd = rsqrtf(var + LN_EPS_F);
        #pragma unroll
        for (int e = 0; e < 4; e++) {
            x[e].x = (x[e].x - mu) * rstd * g4[e].x + be4[e].x;
            x[e].y = (x[e].y - mu) * rstd * g4[e].y + be4[e].y;
            x[e].z = (x[e].z - mu) * rstd * g4[e].z + be4[e].z;
            x[e].w = (x[e].w - mu) * rstd * g4[e].w + be4[e].w;
        }
        float accr[6] = {}, accc[6] = {};
        #pragma unroll
        for (int e = 0; e < 4; e++) {
            #pragma unroll
            for (int d = 0; d < 6; d++) {
                float4 wr = reinterpret_cast<const float4*>(Wr)[d * 256 + l + 64 * e];
                float4 wc = reinterpret_cast<const float4*>(Wc)[d * 256 + l + 64 * e];
                accr[d] += x[e].x*wr.x + x[e].y*wr.y + x[e].z*wr.z + x[e].w*wr.w;
                accc[d] += x[e].x*wc.x + x[e].y*wc.y + x[e].z*wc.z + x[e].w*wc.w;
            }
        }
        float gsum = 0.f, sctx[6];
        #pragma unroll
        for (int d = 0; d < 6; d++) {
            float r = wred(accr[d]);
            float c = wred(accc[d]);
            sctx[d] = c;                       // CLS_CONTEXT_SCALE = 1.0
            gsum += gelu_exact(r + c) * Wsg[d];
        }
        float gate = fast_sigmoid(gsum + bsg[0]);
        if (l < 6)  ws[blk * 8 + l] = sctx[l];
        if (l == 6) ws[blk * 8 + 6] = gate;
    } else {
        float cb[7] = {};
        #pragma unroll
        for (int e = 0; e < 4; e++) {
            float4 be = reinterpret_cast<const float4*>(beta)[l + 64 * e];
            #pragma unroll
            for (int d = 0; d < 7; d++) {
                float4 wv = (d < 6) ? reinterpret_cast<const float4*>(Wr)[d * 256 + l + 64 * e]
                                    : reinterpret_cast<const float4*>(Wtg)[l + 64 * e];
                cb[d] += be.x*wv.x + be.y*wv.y + be.z*wv.z + be.w*wv.w;
            }
        }
        #pragma unroll
        for (int d = 0; d < 7; d++) {
            float c = wred(cb[d]);
            if (l == 0) ws[128 + d] = c;
        }
    }
}

// ---------------- phase 1: attn -> per-token scalars {th[0..5], K} ----------------
// One wave per token; LDS = gamma-folded bf16 weights (14336 B).
// NOTE: on this compiler the 2nd launch_bounds arg caps VGPRs at 256/arg
// (observed: 2->128, 4->64, 5->48). Live set is ~70-80 regs, so arg MUST be 2.
__global__ __launch_bounds__(256, 2) void phase1_kernel(
    const float* __restrict__ attn,
    const float* __restrict__ gamma,
    const float* __restrict__ Wr,     // [6][1024]
    const float* __restrict__ Wtg,    // [1][1024]
    const float* __restrict__ btg,    // [1]
    float* __restrict__ ws)           // in: sctx/gate/CB; out: th-table at WS_TH_BASE
{
    __shared__ __align__(16) unsigned short WT[7 * An];

    const int tid = threadIdx.x;
    const int l   = tid & 63;
    const int w   = tid >> 6;

    for (int i = tid; i < 7 * An; i += 256) {
        int a = i & 1023;
        float wv = (i < 6 * An) ? Wr[i] : Wtg[a];
        WT[i] = f2bf(wv * gamma[a]);
    }

    const int  blk = blockIdx.x;
    const int  b   = blk >> 7;                 // 128 blocks per batch
    const long t0  = (long)blk * TOK_PER_BLK;

    const float sctx0 = ws[b*8+0], sctx1 = ws[b*8+1], sctx2 = ws[b*8+2];
    const float sctx3 = ws[b*8+3], sctx4 = ws[b*8+4], sctx5 = ws[b*8+5];
    const float gate  = ws[b*8+6];
    float CB[7];
    #pragma unroll
    for (int d = 0; d < 7; d++) CB[d] = ws[128 + d];
    const float btg0 = btg[0];

    __syncthreads();

    // per-lane partial row-sums of folded weights
    float gw[7];
    #pragma unroll
    for (int d = 0; d < 7; d++) {
        float acc = 0.f;
        #pragma unroll
        for (int e = 0; e < 4; e++) {
            uint2 u = *reinterpret_cast<const uint2*>(WT + d * An + 4 * l + 256 * e);
            float w0,w1,w2,w3; bf2x(u.x, w0, w1); bf2x(u.y, w2, w3);
            acc += (w0 + w1) + (w2 + w3);
        }
        gw[d] = acc;
    }
    const float sctx[6] = {sctx0, sctx1, sctx2, sctx3, sctx4, sctx5};

    #pragma unroll 1
    for (int it = 0; it < TOK_PER_BLK / 4; ++it) {
        const long t = t0 + w + 4 * it;
        const float4* ar = reinterpret_cast<const float4*>(attn + (size_t)t * An);
        float4 x[4];
        #pragma unroll
        for (int e = 0; e < 4; e++) x[e] = ar[l + 64 * e];

        float s = 0.f, ss = 0.f;
        #pragma unroll
        for (int e = 0; e < 4; e++) {
            s  += x[e].x + x[e].y + x[e].z + x[e].w;
            ss += x[e].x*x[e].x + x[e].y*x[e].y + x[e].z*x[e].z + x[e].w*x[e].w;
        }
        #pragma unroll
        for (int m = 1; m < 64; m <<= 1) { s += __shfl_xor(s, m, 64); ss += __shfl_xor(ss, m, 64); }
        const float mu   = s * (1.f / An);
        const float var  = ss * (1.f / An) - mu * mu;
        const float rstd = rsqrtf(var + LN_EPS_F);

        float p[7] = {};
        #pragma unroll
        for (int e = 0; e < 4; e++) {
            #pragma unroll
            for (int d = 0; d < 7; d++) {
                uint2 u = *reinterpret_cast<const uint2*>(WT + d * An + 4 * l + 256 * e);
                float w0,w1,w2,w3; bf2x(u.x, w0, w1); bf2x(u.y, w2, w3);
                p[d] += x[e].x*w0 + x[e].y*w1 + x[e].z*w2 + x[e].w*w3;
            }
        }
        #pragma unroll
        for (int d = 0; d < 7; d++) p[d] -= mu * gw[d];
        #pragma unroll
        for (int d = 0; d < 7; d++) p[d] = wred(p[d]);

        float th[6];
        #pragma unroll
        for (int d = 0; d < 6; d++) th[d] = gelu_exact(rstd * p[d] + CB[d] + sctx[d]);
        const float tg = fast_sigmoid(rstd * p[6] + CB[6] + btg0);
        const float K  = gate * tg;

        float4* tp = reinterpret_cast<float4*>(ws + WS_TH_BASE + (size_t)t * 8);
        if (l == 0) tp[0] = make_float4(th[0], th[1], th[2], th[3]);
        if (l == 1) tp[1] = make_float4(th[4], th[5], K, 0.f);
    }
}

// ---------------- phase 2: out = hidden * (1 + K * ls * tanh(We . th)) ----------------
// Pure streaming; LDS 17.4 KB. VGPR cap 128 (see note above) -- live set ~45.
__global__ __launch_bounds__(256, 2) void phase2_kernel(
    const float* __restrict__ hidden,
    const float* __restrict__ We,     // [1024][6]
    const float* __restrict__ lsc,    // [1024]
    const float* __restrict__ ws,     // th-table at WS_TH_BASE
    float* __restrict__ out)
{
    __shared__ __align__(16) unsigned short WeT[Dn * Hn]; // [d][h] bf16
    __shared__ __align__(16) float Ls[Hn];
    __shared__ __align__(16) float T[TOK_PER_BLK * 8];

    const int tid = threadIdx.x;
    const int l   = tid & 63;
    const int w   = tid >> 6;
    const long t0 = (long)blockIdx.x * TOK_PER_BLK;

    // stage We transposed: thread handles h-rows (2-way-conflict writes at worst)
    for (int h = tid; h < Hn; h += 256) {
        #pragma unroll
        for (int d = 0; d < Dn; d++) WeT[d * Hn + h] = f2bf(We[h * Dn + d]);
        Ls[h] = lsc[h];
    }
    T[tid] = ws[WS_TH_BASE + t0 * 8 + tid];   // 256 floats = 32 tokens x 8
    __syncthreads();

    #pragma unroll 1
    for (int it = 0; it < TOK_PER_BLK / 4; ++it) {
        const int  tl = w + 4 * it;
        const long t  = t0 + tl;
        const float4 Ta = *reinterpret_cast<const float4*>(&T[tl * 8]);
        const float4 Tb = *reinterpret_cast<const float4*>(&T[tl * 8 + 4]);
        const float th0 = Ta.x, th1 = Ta.y, th2 = Ta.z, th3 = Ta.w;
        const float th4 = Tb.x, th5 = Tb.y, K = Tb.z;

        const float4* hr  = reinterpret_cast<const float4*>(hidden + (size_t)t * Hn);
        float4*       orw = reinterpret_cast<float4*>(out + (size_t)t * Hn);
        #pragma unroll
        for (int e = 0; e < 4; e++) {
            const int idx = l + 64 * e;
            float4 hv = hr[idx];
            float mi0 = 0.f, mi1 = 0.f, mi2 = 0.f, mi3 = 0.f;
            #pragma unroll
            for (int d = 0; d < 6; d++) {
                const float thd = (d==0)?th0:(d==1)?th1:(d==2)?th2:(d==3)?th3:(d==4)?th4:th5;
                uint2 u = *reinterpret_cast<const uint2*>(WeT + d * Hn + 4 * l + 256 * e);
                float w0,w1,w2,w3; bf2x(u.x, w0, w1); bf2x(u.y, w2, w3);
                mi0 += thd*w0; mi1 += thd*w1; mi2 += thd*w2; mi3 += thd*w3;
            }
            float4 lsv = *reinterpret_cast<const float4*>(Ls + 4 * l + 256 * e);
            float4 o;
            o.x = hv.x * (1.f + K * lsv.x * fast_tanh(mi0));
            o.y = hv.y * (1.f + K * lsv.y * fast_tanh(mi1));
            o.z = hv.z * (1.f + K * lsv.z * fast_tanh(mi2));
            o.w = hv.w * (1.f + K * lsv.w * fast_tanh(mi3));
            orw[idx] = o;
        }
    }
}

extern "C" void kernel_launch(void* const* d_in, const int* in_sizes, int n_in,
                              void* d_out, int out_size, void* d_ws, size_t ws_size,
                              hipStream_t stream) {
    const float* hidden = (const float*)d_in[0];
    const float* attn   = (const float*)d_in[1];
    const float* gamma  = (const float*)d_in[2];
    const float* beta   = (const float*)d_in[3];
    const float* Wr     = (const float*)d_in[4];
    const float* Wc     = (const float*)d_in[5];
    const float* We     = (const float*)d_in[6];
    const float* Wtg    = (const float*)d_in[7];
    const float* btg    = (const float*)d_in[8];
    const float* Wsg    = (const float*)d_in[9];
    const float* bsg    = (const float*)d_in[10];
    const float* lsc    = (const float*)d_in[11];
    float* out = (float*)d_out;
    float* ws  = (float*)d_ws;

    pre_kernel<<<dim3(Bn + 1), dim3(64), 0, stream>>>(attn, gamma, beta, Wr, Wc, Wtg, Wsg, bsg, ws);
    phase1_kernel<<<dim3(NBLOCKS), dim3(256), 0, stream>>>(attn, gamma, Wr, Wtg, btg, ws);
    phase2_kernel<<<dim3(NBLOCKS), dim3(256), 0, stream>>>(hidden, We, lsc, ws, out);
}